// Round 1
// 150.850 us; speedup vs baseline: 1.0498x; 1.0498x over previous
//
#include <hip/hip_runtime.h>
#include <hip/hip_bf16.h>

// Problem constants
#define BB 16
#define CC 64
#define HH 64
#define WW 64
#define QQ 8192
#define HID 256
#define KK 576            // C*9
#define HT 66             // H + 2 halo
#define FROW 264          // 257 channels padded to 264 (16B-aligned rows)

typedef short short8 __attribute__((ext_vector_type(8)));
typedef short sv4    __attribute__((ext_vector_type(4)));
typedef float f32x4  __attribute__((ext_vector_type(4)));

__device__ __forceinline__ short f2bf(float f) {
    union { float f; unsigned u; } v; v.f = f;
    unsigned r = v.u + 0x7fffu + ((v.u >> 16) & 1u);
    return (short)(r >> 16);
}
__device__ __forceinline__ float bf2f(short s) {
    union { unsigned u; float f; } v; v.u = ((unsigned)(unsigned short)s) << 16;
    return v.f;
}
// Barrier that only drains LDS (lgkmcnt) — does NOT force vmcnt(0).
__device__ __forceinline__ void barrier_lds() {
    asm volatile("s_waitcnt lgkmcnt(0)" ::: "memory");
    __builtin_amdgcn_s_barrier();
    asm volatile("" ::: "memory");
}
// Async global->LDS DMA, 16B per lane. LDS dest is wave-uniform base +
// lane*16; tracked by vmcnt, drained by __syncthreads.
__device__ __forceinline__ void glld16(const short* g, short* l) {
    __builtin_amdgcn_global_load_lds(
        (const __attribute__((address_space(1))) void*)g,
        (__attribute__((address_space(3))) void*)l, 16, 0, 0);
}

// ---------------------------------------------------------------------------
// Kernel T+P fused: feat transpose (channel-last bf16, zero halo) + weight
// repack into per-K-step contiguous DMA blocks:
//   w3cB[(kchunk)*2176 + n*8 + j] = w3k(n, kchunk*8+j)   (kchunk = kglob>>3)
//   w2cB[(kchunk)*2048 + n*8 + j] = w2[kchunk*8+j][n]
// ---------------------------------------------------------------------------
__global__ __launch_bounds__(256) void prep_transpose_k(const float* __restrict__ feat,
                                                        const float* __restrict__ w2,
                                                        const float* __restrict__ w3,
                                                        const float* __restrict__ b3,
                                                        short* __restrict__ featT,
                                                        short* __restrict__ w3cB,
                                                        short* __restrict__ w2cB) {
    __shared__ float ftile[64][65];
    const int t = threadIdx.x;
    const int gidx = blockIdx.x * 256 + t;   // grid = 1056 wgs

    if (gidx < 156672) {                      // 72 kchunks * 272 n * 8
        int kchunk = gidx / 2176;
        int rem = gidx - kchunk * 2176;
        int n = rem >> 3, j = rem & 7;
        int kglob = kchunk * 8 + j;
        int pos = kglob >> 6, c = kglob & 63;
        float v = 0.f;
        if (n < 256)      v = w3[n * KK + c * 9 + pos];
        else if (n == 256) v = b3[c * 9 + pos];
        w3cB[gidx] = f2bf(v);
    }
    if (gidx < 65536) {                       // 32 kchunks * 256 n * 8
        int kchunk = gidx >> 11;
        int rem = gidx & 2047;
        int n = rem >> 3, j = rem & 7;
        int k = kchunk * 8 + j;
        w2cB[gidx] = f2bf(w2[k * 256 + n]);
    }

    const int b = blockIdx.x / HT;
    const int yy = blockIdx.x - b * HT;
    short* out_row = featT + ((b * HT + yy) * HT) * 64;

    if (yy == 0 || yy == HT - 1) {
        for (int idx = t; idx < HT * 64; idx += 256) out_row[idx] = 0;
        return;
    }
    const int y = yy - 1;
    const float* src = feat + ((b * CC) * HH + y) * WW;
#pragma unroll
    for (int i = 0; i < 16; ++i) {
        int idx = i * 256 + t;
        int c = idx >> 6, x = idx & 63;
        ftile[c][x] = src[c * (HH * WW) + x];
    }
    if (t < 64) out_row[t] = 0;
    else if (t < 128) out_row[(HT - 1) * 64 + (t - 64)] = 0;
    __syncthreads();
#pragma unroll
    for (int i = 0; i < 16; ++i) {
        int idx = i * 256 + t;
        int x = idx >> 6, c = idx & 63;
        out_row[(x + 1) * 64 + c] = f2bf(ftile[c][x]);
    }
}

// ---------------------------------------------------------------------------
// Kernel C v6 (unchanged — proven): m97-style K-loop.
//   wg=(b,y): M=64, N=272, K=576 (18 steps). Per step: DMA next B-tile
//   (17.4 KB) into LDS double-buffer while MFMAs consume current tile.
// ---------------------------------------------------------------------------
#define SSTR 72   // slab row stride (shorts): 144B, 16B-aligned, free 2-way
__global__ __launch_bounds__(256, 2) void conv_k(const short* __restrict__ featT,
                                                 const short* __restrict__ w3cB,
                                                 short* __restrict__ F) {
    __shared__ short slab[3 * HT * SSTR];   // 14,256 shorts = 28,512 B
    __shared__ short Bb[2][8704];           // 2 x 17,408 B
    const int t = threadIdx.x;
    const int wave = t >> 6, lane = t & 63, quad = lane >> 4, ln16 = lane & 15;
    const int b = blockIdx.x >> 6, y = blockIdx.x & 63;

    f32x4 acc[4][5];
#pragma unroll
    for (int a = 0; a < 4; ++a)
#pragma unroll
        for (int i = 0; i < 5; ++i) acc[a][i] = (f32x4){0.f, 0.f, 0.f, 0.f};

    auto stageB = [&](int buf, int st) {
        const short* src = w3cB + st * 8704;
#pragma unroll
        for (int u = 0; u < 5; ++u) {
            int cidx = (u < 4) ? (u * 4 + wave) : 16;
            if (u < 4 || wave == 0)
                glld16(src + cidx * 512 + lane * 8, &Bb[buf][cidx * 512]);
        }
    };

    stageB(0, 0);   // DMA in flight during slab staging

    const short* slabsrc = featT + b * (HT * HT * 64) + y * (HT * 64);
#pragma unroll
    for (int it = 0; it < 7; ++it) {
        int i = it * 256 + t;               // 1584 chunks of 8 shorts
        if (i < 1584) {
            short8 v = *(const short8*)(slabsrc + i * 8);
            int row = i >> 3, cs = (i & 7) * 8;
            *(short8*)(&slab[row * SSTR + cs]) = v;
        }
    }
    __syncthreads();   // drains slab stores (lgkm) + B DMA (vmcnt)

#pragma unroll
    for (int st = 0; st < 18; ++st) {
        const int cur = st & 1;
        if (st < 17) stageB(cur ^ 1, st + 1);
        const int pos = st >> 1, ks = st & 1;
        const int di = pos / 3, dj = pos - di * 3;
        short8 af[4];
#pragma unroll
        for (int ms = 0; ms < 4; ++ms)
            af[ms] = *(const short8*)(&slab[(di * HT + ms * 16 + ln16 + dj) * SSTR + ks * 32 + quad * 8]);
#pragma unroll
        for (int i = 0; i < 5; ++i) {
            int sub = (i < 4) ? (wave + 4 * i) : 16;
            short8 bf = *(const short8*)(&Bb[cur][(quad * 272 + sub * 16 + ln16) * 8]);
#pragma unroll
            for (int ms = 0; ms < 4; ++ms)
                acc[ms][i] = __builtin_amdgcn_mfma_f32_16x16x32_bf16(af[ms], bf, acc[ms][i], 0, 0, 0);
        }
        __syncthreads();
    }

#pragma unroll
    for (int h = 0; h < 2; ++h) {
#pragma unroll
        for (int i = 0; i < 5; ++i) {
            int sub = (i < 4) ? (wave + 4 * i) : 16;
            int n = sub * 16 + ln16;
            bool store = (i < 4) || (wave == 0 && n < FROW);
            if (store) {
#pragma unroll
                for (int ms2 = 0; ms2 < 2; ++ms2) {
                    int ms = h * 2 + ms2;
#pragma unroll
                    for (int r = 0; r < 4; ++r) {
                        int xl = ms2 * 16 + quad * 4 + r;   // local row 0..31
                        slab[xl * FROW + n] = f2bf(acc[ms][i][r]);
                    }
                }
            }
        }
        __syncthreads();
        short8* dst = (short8*)(F + ((long)(b * 64 + y) * 64 + h * 32) * FROW);
        const short8* src8 = (const short8*)slab;
#pragma unroll
        for (int it = 0; it < 5; ++it) {
            int idx = it * 256 + t;
            if (idx < (32 * FROW) / 8) dst[idx] = src8[idx];
        }
        __syncthreads();
    }
}

// ---------------------------------------------------------------------------
// Kernel M v8: barrier-free H2 loop (replaces v7's Wb-DMA 8-step schedule).
//   Insight: each wave only consumed ITS OWN quarter of every staged Wb tile
//   — the LDS staging shared nothing. So: stream w2 L2->registers with a
//   3-deep rolling buffer (wbuf[3][4], 48 VGPRs) and delete the Wb double
//   buffer, all stageW DMA, and all 8 per-step __syncthreads (each of which
//   drained vmcnt(0) and exposed the full DMA latency).
//   - Hh is now full-K (64 x 264 shorts; stride 264 sh = 132 dwords ≡ 4 mod
//     32 -> conflict-free b128 reads AND writes). Written once by all 4
//     waves, made visible by ONE lgkm-only barrier (vmem stays in flight
//     across it -> w2/coord loads keep pipelining).
//   - F gather + b2 loads issued at steps 6/7 of the unrolled loop, where
//     wbuf slots are dying: latency hides under steps 6-7 + combine head
//     without raising peak VGPR.
//   - LDS 51.2 -> 34.8 KB; __launch_bounds__(256,3) caps VGPR at ~170 for a
//     3 wg/CU (12 waves) target, up from the measured ~2 wg effective.
// ---------------------------------------------------------------------------
#define HSTR 264   // Hh row stride (shorts): 528B, 16B-aligned, ≡4 mod 32 dw
__global__ __launch_bounds__(256, 3) void mlp_k(const float* __restrict__ coord,
                                                const float* __restrict__ cell,
                                                const float* __restrict__ w1,
                                                const float* __restrict__ b1,
                                                const float* __restrict__ b2v,
                                                const short* __restrict__ w2cB,
                                                const short* __restrict__ F,
                                                float* __restrict__ out) {
    __shared__ short Hh[64 * HSTR];         // 33,792 B
    __shared__ float red_s[64][4];          // 1,024 B

    const int t = threadIdx.x;
    const int wave = t >> 6, lane = t & 63, quad = lane >> 4, ln16 = lane & 15;
    const int qbase = blockIdx.x * 64;
    const int b = qbase >> 13;              // Q = 8192

    // Rolling w2 fragment loads: step s fragment for this wave is
    //   w2cB[s*8192 + (quad*256 + wave*64 + i*16 + ln16)*8 + j]
    //     = w2[k = s*32 + quad*8 + j][n = wave*64 + i*16 + ln16]
    // i.e. exactly the old Wb read, minus the LDS round-trip.
    short8 wbuf[3][4];
    const short* w2base = w2cB + (quad * 256 + wave * 64 + ln16) * 8;
    auto loadW = [&](int s, int slot) {
#pragma unroll
        for (int i = 0; i < 4; ++i)
            wbuf[slot][i] = *(const short8*)(w2base + s * 8192 + i * 128);
    };

    // --- coords for own query (lane = query) ---
    const int g = qbase + lane;
    const float2 cc = *(const float2*)(coord + g * 2);
    const float2 ce = *(const float2*)(cell + g * 2);

    loadW(0, 0);    // in flight under coord math + H1 compute
    loadW(1, 1);

    const float coy = cc.x - ce.x * 0.5f, cox = cc.y - ce.y * 0.5f;
    const float cqy = fminf(fmaxf(coy + 1e-6f, -0.999999f), 0.999999f);
    const float cqx = fminf(fmaxf(cox + 1e-6f, -0.999999f), 0.999999f);
    int iy = (int)rintf(((cqy + 1.0f) * 64.0f - 1.0f) * 0.5f); iy = min(max(iy, 0), 63);
    int ix = (int)rintf(((cqx + 1.0f) * 64.0f - 1.0f) * 0.5f); ix = min(max(ix, 0), 63);
    const int lin = iy * 64 + ix;
    const float in0 = (coy - ((float)iy * (1.0f / 32.0f) - 1.0f)) * 32.0f;
    const float in1 = (cox - ((float)ix * (1.0f / 32.0f) - 1.0f)) * 32.0f;
    const float in2 = ce.x * 32.0f;

    // gather rows for the combine (lane ln16 of group ms owns query ms*16+ln16)
    int linm[4];
#pragma unroll
    for (int ms = 0; ms < 4; ++ms) linm[ms] = __shfl(lin, ms * 16 + ln16, 64);

    // --- H1 for own query, own wave's k-slice [wave*64, wave*64+64) -> regs
    short8 hv[8];
    const int k0w = wave * 64;
#pragma unroll
    for (int c8 = 0; c8 < 8; ++c8) {
        const int k0 = k0w + c8 * 8;
        f32x4 wa0 = *(const f32x4*)(w1 + k0),       wa1 = *(const f32x4*)(w1 + k0 + 4);
        f32x4 wb0 = *(const f32x4*)(w1 + 256 + k0), wb1 = *(const f32x4*)(w1 + 256 + k0 + 4);
        f32x4 wc0 = *(const f32x4*)(w1 + 512 + k0), wc1 = *(const f32x4*)(w1 + 512 + k0 + 4);
        f32x4 bb0 = *(const f32x4*)(b1 + k0),       bb1 = *(const f32x4*)(b1 + k0 + 4);
#pragma unroll
        for (int jj = 0; jj < 4; ++jj) {
            float v0 = fmaf(in0, wa0[jj], fmaf(in1, wb0[jj], fmaf(in2, wc0[jj], bb0[jj])));
            float v1 = fmaf(in0, wa1[jj], fmaf(in1, wb1[jj], fmaf(in2, wc1[jj], bb1[jj])));
            hv[c8][jj]     = f2bf(fmaxf(v0, 0.f));
            hv[c8][jj + 4] = f2bf(fmaxf(v1, 0.f));
        }
    }
    // all 4 waves write their full k-slice; ONE lgkm-only barrier.
    // (16B/lane at 528B stride: 8 lanes cover all 32 banks exactly -> free)
#pragma unroll
    for (int c8 = 0; c8 < 8; ++c8)
        *(short8*)(&Hh[lane * HSTR + wave * 64 + c8 * 8]) = hv[c8];
    barrier_lds();   // vmem (wbuf loads) stays in flight across this

    // --- H2^T MFMA loop: no barriers, no LDS staging ---
    const short* Fb = F + (long)b * 4096 * FROW;
    sv4 fv[4][4];
    short fbs = 0;
    f32x4 b2q[4];
    f32x4 acc2[4][4];
#pragma unroll
    for (int i = 0; i < 4; ++i)
#pragma unroll
        for (int ms = 0; ms < 4; ++ms) acc2[i][ms] = (f32x4){0.f, 0.f, 0.f, 0.f};

#pragma unroll
    for (int s = 0; s < 8; ++s) {
        if (s < 6) loadW(s + 2, (s + 2) % 3);   // keep 2 K-steps in flight
        short8 hf[4];
#pragma unroll
        for (int ms = 0; ms < 4; ++ms)
            hf[ms] = *(const short8*)(&Hh[(ms * 16 + ln16) * HSTR + s * 32 + quad * 8]);
        if (s == 6) {
            // F gather issued here: wbuf slots mostly dead, so peak VGPR is
            // safe; latency hides under steps 6-7 + combine head.
#pragma unroll
            for (int ms = 0; ms < 4; ++ms) {
                const short* Fr = Fb + (long)linm[ms] * FROW + wave * 64 + quad * 4;
#pragma unroll
                for (int i = 0; i < 4; ++i) fv[ms][i] = *(const sv4*)(Fr + i * 16);
            }
            fbs = Fb[(long)lin * FROW + 256];
        }
        if (s == 7) {
#pragma unroll
            for (int i = 0; i < 4; ++i)
                b2q[i] = *(const f32x4*)(b2v + wave * 64 + i * 16 + quad * 4);
        }
#pragma unroll
        for (int i = 0; i < 4; ++i)
#pragma unroll
            for (int ms = 0; ms < 4; ++ms)
                acc2[i][ms] = __builtin_amdgcn_mfma_f32_16x16x32_bf16(wbuf[s % 3][i], hf[ms], acc2[i][ms], 0, 0, 0);
    }

    // --- combine: pred[m] += relu(H2[n][m]+b2[n]) * F[lin[m]][n] ---
    const float fbv = bf2f(fbs);
    float part[4] = {0.f, 0.f, 0.f, 0.f};
#pragma unroll
    for (int i = 0; i < 4; ++i)
#pragma unroll
        for (int ms = 0; ms < 4; ++ms)
#pragma unroll
            for (int r = 0; r < 4; ++r)
                part[ms] = fmaf(fmaxf(acc2[i][ms][r] + b2q[i][r], 0.f), bf2f(fv[ms][i][r]), part[ms]);
#pragma unroll
    for (int ms = 0; ms < 4; ++ms) {
        part[ms] += __shfl_xor(part[ms], 16, 64);
        part[ms] += __shfl_xor(part[ms], 32, 64);
    }
    if (quad == 0) {
#pragma unroll
        for (int ms = 0; ms < 4; ++ms) red_s[ms * 16 + ln16][wave] = part[ms];
    }
    barrier_lds();
    if (t < 64)
        out[qbase + t] = red_s[t][0] + red_s[t][1] + red_s[t][2] + red_s[t][3] + fbv;
}

// ---------------------------------------------------------------------------
extern "C" void kernel_launch(void* const* d_in, const int* in_sizes, int n_in,
                              void* d_out, int out_size, void* d_ws, size_t ws_size,
                              hipStream_t stream) {
    const float* feat  = (const float*)d_in[0];
    const float* coord = (const float*)d_in[1];
    const float* cell  = (const float*)d_in[2];
    const float* w1    = (const float*)d_in[3];
    const float* b1    = (const float*)d_in[4];
    const float* w2    = (const float*)d_in[5];
    const float* b2    = (const float*)d_in[6];
    const float* w3    = (const float*)d_in[7];
    const float* b3    = (const float*)d_in[8];
    float* out = (float*)d_out;

    char* ws = (char*)d_ws;
    short* w3cB  = (short*)(ws);                       // 72*2176*2      = 313,344
    short* w2cB  = (short*)(ws + 313344);              // 32*2048*2      = 131,072
    short* featT = (short*)(ws + 444416);              // 16*66*66*64*2  = 8,921,088
    short* F     = (short*)(ws + 9365504);             // 16*4096*264*2  = 34,603,008
    (void)ws_size; (void)in_sizes; (void)n_in; (void)out_size;

    prep_transpose_k<<<BB * HT, 256, 0, stream>>>(feat, w2, w3, b3, featT, w3cB, w2cB);
    conv_k<<<BB * HH, 256, 0, stream>>>(featT, w3cB, F);
    mlp_k<<<(BB * QQ) / 64, 256, 0, stream>>>(coord, cell, w1, b1, b2, w2cB, F, out);
}